// Round 7
// baseline (500.114 us; speedup 1.0000x reference)
//
#include <hip/hip_runtime.h>
#include <hip/hip_bf16.h>
#include <math.h>

// ---------------------------------------------------------------------------
// GINE model: 3x (GINEConv + BN + ReLU) -> global mean pool -> MLP -> sigmoid
// Round 7: channel-interleaved edge kernel (8B h-gathers), NT-tile loop with
// prefetch, fused preprocessing (2-level scan, one weights-prep kernel).
// ---------------------------------------------------------------------------

typedef __attribute__((ext_vector_type(8))) short short8v;
typedef __attribute__((ext_vector_type(4))) float f32x4;
typedef __attribute__((ext_vector_type(4))) unsigned short us4;

static __device__ __forceinline__ float bf2f(unsigned short u) {
    union { unsigned int u32; float f; } c; c.u32 = ((unsigned int)u) << 16; return c.f;
}
static __device__ __forceinline__ unsigned short f2bf(float f) {
    union { float f; unsigned int u; } c; c.f = f;
    unsigned int lsb = (c.u >> 16) & 1u;
    c.u += 0x7fffu + lsb;
    return (unsigned short)(c.u >> 16);
}

__global__ void k_zero_i(int* __restrict__ p, int n) {
    int i = blockIdx.x * blockDim.x + threadIdx.x;
    int st = gridDim.x * blockDim.x;
    for (; i < n; i += st) p[i] = 0;
}

// dst histogram (blocks 0..511) + batch histogram (blocks 512..639)
__global__ void k_hist2(const int* __restrict__ dst, int E,
                        const int* __restrict__ batch, int N,
                        int* __restrict__ ideg, int* __restrict__ gcnt) {
    int b = blockIdx.x;
    if (b < 512) {
        int i = b * 256 + threadIdx.x, st = 512 * 256;
        for (; i < E; i += st) atomicAdd(&ideg[dst[i]], 1);
    } else {
        int i = (b - 512) * 256 + threadIdx.x, st = 128 * 256;
        for (; i < N; i += st) atomicAdd(&gcnt[batch[i]], 1);
    }
}

// single-block two-level exclusive scan; writes out[n]=total, optional 2nd copy
static __device__ void scan_block(const int* __restrict__ in, int* __restrict__ out,
                                  int* __restrict__ out2, int n, int* wsum) {
    const int tid = threadIdx.x;
    const int lane = tid & 63, wv = tid >> 6;
    const int C = (n + 1023) >> 10;
    const int base = tid * C;
    int s = 0;
    for (int k = 0; k < C; ++k) {
        int i = base + k;
        if (i < n) s += in[i];
    }
    int incl = s;
#pragma unroll
    for (int off = 1; off < 64; off <<= 1) {
        int t = __shfl_up(incl, off);
        if (lane >= off) incl += t;
    }
    if (lane == 63) wsum[wv] = incl;
    __syncthreads();
    int woff = 0;
    for (int i2 = 0; i2 < wv; ++i2) woff += wsum[i2];
    int excl = woff + incl - s;
    int run = excl;
    for (int k = 0; k < C; ++k) {
        int i = base + k;
        if (i < n) {
            out[i] = run;
            if (out2) out2[i] = run;
            run += in[i];
        }
    }
    if (tid == 1023) out[n] = run;
    __syncthreads();
}

__global__ __launch_bounds__(1024) void k_scan_all(
    const int* __restrict__ ideg, int* __restrict__ rowptr, int* __restrict__ cursor, int n1,
    const int* __restrict__ gcnt, int* __restrict__ gptr, int n2) {
    __shared__ int wsum[16];
    scan_block(ideg, rowptr, cursor, n1, wsum);
    scan_block(gcnt, gptr, nullptr, n2, wsum);
}

// bucket edges by dst + pad tail [E, Epad)
__global__ void k_scatter(const int* __restrict__ ei, int E, int Epad,
                          int* __restrict__ cursor, int* __restrict__ eid_s,
                          int* __restrict__ esrc_s, int* __restrict__ dst_s,
                          unsigned short* __restrict__ ea_s) {
    int i = blockIdx.x * blockDim.x + threadIdx.x;
    int st = gridDim.x * blockDim.x;
    for (int k = i; k < E; k += st) {
        int d = ei[E + k];
        int pos = atomicAdd(&cursor[d], 1);
        eid_s[pos] = k;
        esrc_s[pos] = ei[k];
        dst_s[pos] = d;
    }
    if (i < Epad - E) {
        esrc_s[E + i] = 0;
        dst_s[E + i] = -1;
        us4 z = {0, 0, 0, 0};
        us4* p = (us4*)(ea_s + (size_t)(E + i) * 32);
#pragma unroll
        for (int q = 0; q < 8; ++q) p[q] = z;
    }
}

// ea_s[pos] = bf16(ea[eid_s[pos]]), CSR order
__global__ void k_permute_ea(const float* __restrict__ ea, const int* __restrict__ eid_s,
                             unsigned short* __restrict__ ea_s, int E) {
    int i = blockIdx.x * blockDim.x + threadIdx.x;
    int st = gridDim.x * blockDim.x;
    const int ng = E * 4;
    for (; i < ng; i += st) {
        int pos = i >> 2, q = i & 3;
        int e = eid_s[pos];
        const float4* sp = (const float4*)(ea + (size_t)e * 32 + q * 8);
        float4 a = sp[0], b = sp[1];
        us4 o0, o1;
        o0.x = f2bf(a.x); o0.y = f2bf(a.y); o0.z = f2bf(a.z); o0.w = f2bf(a.w);
        o1.x = f2bf(b.x); o1.y = f2bf(b.y); o1.z = f2bf(b.z); o1.w = f2bf(b.w);
        us4* dp = (us4*)(ea_s + (size_t)pos * 32 + q * 8);
        dp[0] = o0; dp[1] = o1;
    }
}

// all weight prep in one launch: bf16 casts of we1/2/3, wn1/2/3 + w4 transpose
__global__ void k_wprep(const float* __restrict__ we1, const float* __restrict__ we2,
                        const float* __restrict__ we3, const float* __restrict__ wn1,
                        const float* __restrict__ wn2, const float* __restrict__ wn3,
                        const float* __restrict__ w4,
                        unsigned short* __restrict__ webf1, unsigned short* __restrict__ webf2,
                        unsigned short* __restrict__ webf3, unsigned short* __restrict__ wnbf1,
                        unsigned short* __restrict__ wnbf2, unsigned short* __restrict__ wnbf3,
                        float* __restrict__ w4t) {
    int idx = blockIdx.x * blockDim.x + threadIdx.x;
    const float* s; unsigned short* d; int rel;
    if (idx < 512)        { s = we1; d = webf1; rel = idx; }
    else if (idx < 2560)  { s = we2; d = webf2; rel = idx - 512; }
    else if (idx < 4608)  { s = we3; d = webf3; rel = idx - 2560; }
    else if (idx < 8704)  { s = wn1; d = wnbf1; rel = idx - 4608; }
    else if (idx < 25088) { s = wn2; d = wnbf2; rel = idx - 8704; }
    else if (idx < 41472) { s = wn3; d = wnbf3; rel = idx - 25088; }
    else if (idx < 49664) {
        int rel2 = idx - 41472;
        int k = rel2 >> 5;
        int j0 = (rel2 & 31) * 4;
        float4 o;
        o.x = w4[(j0 + 0) * 256 + k]; o.y = w4[(j0 + 1) * 256 + k];
        o.z = w4[(j0 + 2) * 256 + k]; o.w = w4[(j0 + 3) * 256 + k];
        *(float4*)(w4t + k * 128 + j0) = o;
        return;
    } else return;
    float4 t = ((const float4*)s)[rel];
    us4 o; o.x = f2bf(t.x); o.y = f2bf(t.y); o.z = f2bf(t.z); o.w = f2bf(t.w);
    ((us4*)d)[rel] = o;
}

// x -> bf16 + f32 self-term init in one pass
__global__ void k_xprep(const float* __restrict__ x, unsigned short* __restrict__ x_bf,
                        float* __restrict__ aggrA, int n4) {
    int i = blockIdx.x * blockDim.x + threadIdx.x;
    int st = gridDim.x * blockDim.x;
    for (; i < n4; i += st) {
        float4 t = ((const float4*)x)[i];
        us4 o; o.x = f2bf(t.x); o.y = f2bf(t.y); o.z = f2bf(t.z); o.w = f2bf(t.w);
        ((us4*)x_bf)[i] = o;
        ((float4*)aggrA)[i] = t;
    }
}

// ---------------------------------------------------------------------------
// Edge kernel, round 7. Channel-interleaved: MFMA col-tile t, col j = channel
// colbase + j*4 + t  ->  per-lane h-gather = one 8B us4 load per (q,i).
// NT consecutive 64-edge tiles per wave, next-tile prefetch, persistent bfr.
// aggr must be pre-initialized with the self term (f32).
// ---------------------------------------------------------------------------
template<int D, int NT>
__global__ __launch_bounds__(256) void k_edge_mfma(
    const unsigned short* __restrict__ hbf,   // [N][D] bf16
    const unsigned short* __restrict__ ea_s,  // [Epad][32] bf16, CSR order
    const int* __restrict__ esrc_s,           // [Epad]
    const int* __restrict__ dst_s,            // [Epad]
    const unsigned short* __restrict__ webf,  // [D][32] bf16
    const float* __restrict__ be,             // [D]
    float* __restrict__ aggr,                 // [N][D] f32
    int E)
{
    const int tid = threadIdx.x;
    const int lane = tid & 63;
    const int w = tid >> 6;
    const int l15 = lane & 15;
    const int lhi = lane >> 4;
    const int colbase = (D == 256) ? (w * 64) : 0;

    int first;
    if (D == 256) first = blockIdx.x * (NT * 64);
    else          first = (blockIdx.x * 4 + w) * (NT * 64);
    if (first >= E) return;
    const int ntile = min(NT, (E - first + 63) >> 6);

    // persistent B fragments + bias; channel c = colbase + l15*4 + t
    short8v bfr[4]; float bias[4];
#pragma unroll
    for (int t = 0; t < 4; ++t) {
        int c = colbase + l15 * 4 + t;
        bfr[t] = *(const short8v*)(webf + (size_t)c * 32 + lhi * 8);
        bias[t] = be[c];
    }

    // prefetch tile 0
    int e0 = first;
    int4 src4[4]; short8v afr[4];
#pragma unroll
    for (int q = 0; q < 4; ++q) src4[q] = *(const int4*)(esrc_s + e0 + q * 16 + lhi * 4);
    int dstreg = dst_s[e0 + lane];
#pragma unroll
    for (int q = 0; q < 4; ++q)
        afr[q] = *(const short8v*)(ea_s + (size_t)(e0 + q * 16 + l15) * 32 + lhi * 8);

    for (int j = 0; j < ntile; ++j) {
        // issue h gathers for current tile (8B each)
        us4 hv[4][4];
#pragma unroll
        for (int q = 0; q < 4; ++q) {
            const int sr[4] = {src4[q].x, src4[q].y, src4[q].z, src4[q].w};
#pragma unroll
            for (int i = 0; i < 4; ++i)
                hv[q][i] = *(const us4*)(hbf + (size_t)sr[i] * D + colbase + l15 * 4);
        }

        // prefetch next tile (clamped on last iteration; values then unused)
        const int ne0 = first + min(j + 1, ntile - 1) * 64;
        int4 nsrc4[4]; short8v nafr[4];
#pragma unroll
        for (int q = 0; q < 4; ++q) nsrc4[q] = *(const int4*)(esrc_s + ne0 + q * 16 + lhi * 4);
        int ndst = dst_s[ne0 + lane];
#pragma unroll
        for (int q = 0; q < 4; ++q)
            nafr[q] = *(const short8v*)(ea_s + (size_t)(ne0 + q * 16 + l15) * 32 + lhi * 8);

        // MFMA (independent of hv), bias in C-init
        f32x4 acc[4][4];
#pragma unroll
        for (int q = 0; q < 4; ++q)
#pragma unroll
            for (int t = 0; t < 4; ++t) {
                f32x4 ci; ci[0] = bias[t]; ci[1] = bias[t]; ci[2] = bias[t]; ci[3] = bias[t];
                acc[q][t] = __builtin_amdgcn_mfma_f32_16x16x32_bf16(afr[q], bfr[t], ci, 0, 0, 0);
            }

        // m = relu(el + h_src)
#pragma unroll
        for (int q = 0; q < 4; ++q)
#pragma unroll
            for (int i = 0; i < 4; ++i) {
                us4 h4 = hv[q][i];
#pragma unroll
                for (int t = 0; t < 4; ++t)
                    acc[q][t][i] = fmaxf(acc[q][t][i] + bf2f(h4[t]), 0.0f);
            }

        // segmented flush over sorted dst
        int dprev = __shfl_up(dstreg, 1);
        bool bflag = (lane > 0) && (dstreg != dprev);
        unsigned long long bmask = __ballot(bflag);
        const int nseg = __builtin_popcountll(bmask) + 1;
        unsigned mlo = (unsigned)bmask, mhi = (unsigned)(bmask >> 32);
        const int segid_lane =
            __builtin_amdgcn_mbcnt_hi(mhi, __builtin_amdgcn_mbcnt_lo(mlo, 0)) + (bflag ? 1 : 0);

        int segid_qi[4][4];
#pragma unroll
        for (int q = 0; q < 4; ++q)
#pragma unroll
            for (int i = 0; i < 4; ++i) {
                int row = q * 16 + lhi * 4 + i;
                unsigned long long p = 1ull << row;
                segid_qi[q][i] = __builtin_popcountll(bmask & (p | (p - 1ull)));
            }

        for (int s = 0; s < nseg; ++s) {
            float a[4] = {0.0f, 0.0f, 0.0f, 0.0f};
#pragma unroll
            for (int q = 0; q < 4; ++q)
#pragma unroll
                for (int i = 0; i < 4; ++i) {
                    bool tk = (segid_qi[q][i] == s);
#pragma unroll
                    for (int t = 0; t < 4; ++t) a[t] += tk ? acc[q][t][i] : 0.0f;
                }
#pragma unroll
            for (int t = 0; t < 4; ++t) {
                a[t] += __shfl_xor(a[t], 16);
                a[t] += __shfl_xor(a[t], 32);
            }
            unsigned long long ms = __ballot(segid_lane == s);
            int fl = (int)__builtin_ctzll(ms);
            int dseg = __shfl(dstreg, fl);
            if (dseg >= 0 && lhi == 0) {
#pragma unroll
                for (int t = 0; t < 4; ++t)
                    atomicAdd(aggr + (size_t)dseg * D + colbase + l15 * 4 + t, a[t]);
            }
        }

        // rotate prefetched state
        e0 = ne0; dstreg = ndst;
#pragma unroll
        for (int q = 0; q < 4; ++q) { src4[q] = nsrc4[q]; afr[q] = nafr[q]; }
    }
}

// ---------------------------------------------------------------------------
// MFMA node GEMM + BN + ReLU (round 6, unchanged).
// ---------------------------------------------------------------------------
template<int K, bool AW>
__global__ __launch_bounds__(256) void k_node_mfma(
    const float* __restrict__ A, const unsigned short* __restrict__ wnbf,
    const float* __restrict__ bnb, const float* __restrict__ g,
    const float* __restrict__ b, const float* __restrict__ rm,
    const float* __restrict__ rv, unsigned short* __restrict__ out,
    float* __restrict__ aggr_out, int N)
{
    const int tid = threadIdx.x;
    const int lane = tid & 63;
    const int w = tid >> 6;
    const int l15 = lane & 15;
    const int lhi = lane >> 4;
    const int row0 = blockIdx.x * 64;
    const int ncol0 = w * 64;

    f32x4 scale[4], shift[4];
    f32x4 acc[4][4];
#pragma unroll
    for (int q = 0; q < 4; ++q) {
        int n0 = ncol0 + q * 16 + lhi * 4;
        float4 gg = *(const float4*)(g + n0);
        float4 rvv = *(const float4*)(rv + n0);
        float4 bb = *(const float4*)(b + n0);
        float4 rmm = *(const float4*)(rm + n0);
        float4 bn = *(const float4*)(bnb + n0);
        f32x4 sc, sh, ci;
        sc[0] = gg.x * rsqrtf(rvv.x + 1e-5f);
        sc[1] = gg.y * rsqrtf(rvv.y + 1e-5f);
        sc[2] = gg.z * rsqrtf(rvv.z + 1e-5f);
        sc[3] = gg.w * rsqrtf(rvv.w + 1e-5f);
        sh[0] = bb.x - rmm.x * sc[0];
        sh[1] = bb.y - rmm.y * sc[1];
        sh[2] = bb.z - rmm.z * sc[2];
        sh[3] = bb.w - rmm.w * sc[3];
        ci[0] = bn.x; ci[1] = bn.y; ci[2] = bn.z; ci[3] = bn.w;
        scale[q] = sc; shift[q] = sh;
#pragma unroll
        for (int r = 0; r < 4; ++r) acc[q][r] = ci;
    }

    for (int k0 = 0; k0 < K; k0 += 32) {
        short8v wfr[4];
#pragma unroll
        for (int q = 0; q < 4; ++q)
            wfr[q] = *(const short8v*)(wnbf + (size_t)(ncol0 + q * 16 + l15) * K + k0 + lhi * 8);
        short8v afr[4];
#pragma unroll
        for (int r = 0; r < 4; ++r) {
            const float* ap = A + (size_t)(row0 + r * 16 + l15) * K + k0 + lhi * 8;
            float4 a0 = ((const float4*)ap)[0];
            float4 a1 = ((const float4*)ap)[1];
            short8v t;
            t[0] = (short)f2bf(a0.x); t[1] = (short)f2bf(a0.y);
            t[2] = (short)f2bf(a0.z); t[3] = (short)f2bf(a0.w);
            t[4] = (short)f2bf(a1.x); t[5] = (short)f2bf(a1.y);
            t[6] = (short)f2bf(a1.z); t[7] = (short)f2bf(a1.w);
            afr[r] = t;
        }
#pragma unroll
        for (int q = 0; q < 4; ++q)
#pragma unroll
            for (int r = 0; r < 4; ++r)
                acc[q][r] = __builtin_amdgcn_mfma_f32_16x16x32_bf16(wfr[q], afr[r], acc[q][r], 0, 0, 0);
    }

#pragma unroll
    for (int r = 0; r < 4; ++r) {
        int m = row0 + r * 16 + l15;
        if (m < N) {
#pragma unroll
            for (int q = 0; q < 4; ++q) {
                int n0 = ncol0 + q * 16 + lhi * 4;
                f32x4 v = acc[q][r];
                f32x4 o;
#pragma unroll
                for (int i = 0; i < 4; ++i)
                    o[i] = fmaxf(v[i] * scale[q][i] + shift[q][i], 0.0f);
                us4 ob;
                ob.x = f2bf(o[0]); ob.y = f2bf(o[1]); ob.z = f2bf(o[2]); ob.w = f2bf(o[3]);
                *(us4*)(out + (size_t)m * 256 + n0) = ob;
                if (AW) *(f32x4*)(aggr_out + (size_t)m * 256 + n0) = o;
            }
        }
    }
}

// Fused global-mean-pool + MLP head (h in bf16).
__global__ __launch_bounds__(256) void k_pool_head(
    const unsigned short* __restrict__ h, const int* __restrict__ gptr,
    const float* __restrict__ w4t, const float* __restrict__ b4,
    const float* __restrict__ w5, const float* __restrict__ b5,
    float* __restrict__ out)
{
    __shared__ float pl[256];
    __shared__ float zs[128];
    const int g = blockIdx.x;
    const int tid = threadIdx.x;
    int beg = gptr[g], end = gptr[g + 1];
    float acc = 0.0f;
    for (int r = beg; r < end; ++r) acc += bf2f(h[(size_t)r * 256 + tid]);
    float cnt = (float)(end - beg);
    pl[tid] = acc / fmaxf(cnt, 1.0f);
    __syncthreads();
    if (tid < 128) {
        float a = b4[tid];
        for (int k = 0; k < 256; ++k) a += pl[k] * w4t[k * 128 + tid];
        zs[tid] = fmaxf(a, 0.0f);
    }
    __syncthreads();
    if (tid < 64) {
        float v = zs[tid] * w5[tid] + zs[tid + 64] * w5[tid + 64];
#pragma unroll
        for (int off = 32; off > 0; off >>= 1) v += __shfl_down(v, off);
        if (tid == 0) out[g] = 1.0f / (1.0f + expf(-(v + b5[0])));
    }
}

extern "C" void kernel_launch(void* const* d_in, const int* in_sizes, int n_in,
                              void* d_out, int out_size, void* d_ws, size_t ws_size,
                              hipStream_t stream)
{
    const float* x    = (const float*)d_in[0];
    const int*   ei   = (const int*)d_in[1];
    const float* ea   = (const float*)d_in[2];
    const int*   batch= (const int*)d_in[3];
    const float* we1  = (const float*)d_in[4];
    const float* be1  = (const float*)d_in[5];
    const float* wn1  = (const float*)d_in[6];
    const float* bnb1 = (const float*)d_in[7];
    const float* we2  = (const float*)d_in[8];
    const float* be2  = (const float*)d_in[9];
    const float* wn2  = (const float*)d_in[10];
    const float* bnb2 = (const float*)d_in[11];
    const float* we3  = (const float*)d_in[12];
    const float* be3  = (const float*)d_in[13];
    const float* wn3  = (const float*)d_in[14];
    const float* bnb3 = (const float*)d_in[15];
    const float* g1 = (const float*)d_in[16];
    const float* b1 = (const float*)d_in[17];
    const float* rm1= (const float*)d_in[18];
    const float* rv1= (const float*)d_in[19];
    const float* g2 = (const float*)d_in[20];
    const float* b2 = (const float*)d_in[21];
    const float* rm2= (const float*)d_in[22];
    const float* rv2= (const float*)d_in[23];
    const float* g3 = (const float*)d_in[24];
    const float* b3 = (const float*)d_in[25];
    const float* rm3= (const float*)d_in[26];
    const float* rv3= (const float*)d_in[27];
    const float* w4 = (const float*)d_in[28];
    const float* b4 = (const float*)d_in[29];
    const float* w5 = (const float*)d_in[30];
    const float* b5 = (const float*)d_in[31];

    const int N = in_sizes[0] / 64;
    const int E = in_sizes[1] / 2;
    const int G = out_size;
    const int Epad = (E + 63) & ~63;

    // ---- workspace layout ----
    float* ws    = (float*)d_ws;
    float* aggrA = ws;                                  // N*256 f32
    float* aggrB = aggrA + (size_t)N * 256;             // N*256 f32
    float* w4t   = aggrB + (size_t)N * 256;             // 256*128
    unsigned short* ea_s  = (unsigned short*)(w4t + 256 * 128);   // Epad*32 bf16
    unsigned short* x_bf  = ea_s + (size_t)Epad * 32;   // N*64 bf16
    unsigned short* h_bf  = x_bf + (size_t)N * 64;      // N*256 bf16
    unsigned short* webf1 = h_bf + (size_t)N * 256;     // 64*32 bf16
    unsigned short* webf2 = webf1 + 64 * 32;            // 256*32
    unsigned short* webf3 = webf2 + 256 * 32;           // 256*32
    unsigned short* wnbf1 = webf3 + 256 * 32;           // 256*64 bf16
    unsigned short* wnbf2 = wnbf1 + 256 * 64;           // 256*256
    unsigned short* wnbf3 = wnbf2 + 256 * 256;          // 256*256
    int* iws    = (int*)(wnbf3 + 256 * 256);
    int* ideg   = iws;                                  // N   (gcnt adjacent!)
    int* gcnt   = ideg + N;                             // G
    int* rowptr = gcnt + G;                             // N+1
    int* gptr   = rowptr + N + 1;                       // G+1
    int* cursor = gptr + G + 1;                         // N
    int* eid_s  = cursor + N;                           // E
    int* esrc_s = eid_s + E;                            // Epad
    int* dst_s  = esrc_s + Epad;                        // Epad

    const int nblk64 = (N + 63) / 64;
    const int ntiles = Epad / 64;                       // 64-edge tiles
    constexpr int NT = 4;
    const int eblk256 = (ntiles + NT - 1) / NT;
    const int eblk64  = (ntiles + 4 * NT - 1) / (4 * NT);

    // ---- fused preprocessing ----
    k_zero_i<<<64, 256, 0, stream>>>(ideg, N + G);
    k_hist2<<<640, 256, 0, stream>>>(ei + E, E, batch, N, ideg, gcnt);
    k_scan_all<<<1, 1024, 0, stream>>>(ideg, rowptr, cursor, N, gcnt, gptr, G);
    k_scatter<<<512, 256, 0, stream>>>(ei, E, Epad, cursor, eid_s, esrc_s, dst_s, ea_s);
    k_permute_ea<<<2048, 256, 0, stream>>>(ea, eid_s, ea_s, E);
    k_wprep<<<194, 256, 0, stream>>>(we1, we2, we3, wn1, wn2, wn3, w4,
                                     webf1, webf2, webf3, wnbf1, wnbf2, wnbf3, w4t);
    k_xprep<<<1250, 256, 0, stream>>>(x, x_bf, aggrA, N * 16);

    // ---- Layer 1 (D=64) ----
    k_edge_mfma<64, NT><<<eblk64, 256, 0, stream>>>(
        x_bf, ea_s, esrc_s, dst_s, webf1, be1, aggrA, E);
    k_node_mfma<64, true><<<nblk64, 256, 0, stream>>>(aggrA, wnbf1, bnb1, g1, b1, rm1, rv1,
                                                      h_bf, aggrB, N);

    // ---- Layer 2 (D=256) ----
    k_edge_mfma<256, NT><<<eblk256, 256, 0, stream>>>(
        h_bf, ea_s, esrc_s, dst_s, webf2, be2, aggrB, E);
    k_node_mfma<256, true><<<nblk64, 256, 0, stream>>>(aggrB, wnbf2, bnb2, g2, b2, rm2, rv2,
                                                       h_bf, aggrA, N);

    // ---- Layer 3 (D=256) ----
    k_edge_mfma<256, NT><<<eblk256, 256, 0, stream>>>(
        h_bf, ea_s, esrc_s, dst_s, webf3, be3, aggrA, E);
    k_node_mfma<256, false><<<nblk64, 256, 0, stream>>>(aggrA, wnbf3, bnb3, g3, b3, rm3, rv3,
                                                        h_bf, (float*)nullptr, N);

    // ---- Fused pool + head ----
    k_pool_head<<<G, 256, 0, stream>>>(h_bf, gptr, w4t, b4, w5, b5, (float*)d_out);
}

// Round 9
// 335.306 us; speedup vs baseline: 1.4915x; 1.4915x over previous
//
#include <hip/hip_runtime.h>
#include <hip/hip_bf16.h>
#include <math.h>

// ---------------------------------------------------------------------------
// GINE model: 3x (GINEConv + BN + ReLU) -> global mean pool -> MLP -> sigmoid
// Round 8 (resubmit; previous run died to an unresponsive container):
// permuted h/x channel layout (within each 64-block, position p holds channel
// (p&3)*16 + (p>>2)) -> edge h-gather is one us4/8B load per fragment row,
// while the segment flush keeps round-6's contiguous-64B atomics on the
// natural-layout aggr. No NT prefetch (restores occupancy). Node GEMM stores
// h via 2x16B permuted stores.
// ---------------------------------------------------------------------------

typedef __attribute__((ext_vector_type(8))) short short8v;
typedef __attribute__((ext_vector_type(4))) float f32x4;
typedef __attribute__((ext_vector_type(4))) unsigned short us4;
typedef __attribute__((ext_vector_type(8))) unsigned short us8;

static __device__ __forceinline__ float bf2f(unsigned short u) {
    union { unsigned int u32; float f; } c; c.u32 = ((unsigned int)u) << 16; return c.f;
}
static __device__ __forceinline__ unsigned short f2bf(float f) {
    union { float f; unsigned int u; } c; c.f = f;
    unsigned int lsb = (c.u >> 16) & 1u;
    c.u += 0x7fffu + lsb;
    return (unsigned short)(c.u >> 16);
}

__global__ void k_zero_i(int* __restrict__ p, int n) {
    int i = blockIdx.x * blockDim.x + threadIdx.x;
    int st = gridDim.x * blockDim.x;
    for (; i < n; i += st) p[i] = 0;
}

// dst histogram (blocks 0..511) + batch histogram (blocks 512..639)
__global__ void k_hist2(const int* __restrict__ dst, int E,
                        const int* __restrict__ batch, int N,
                        int* __restrict__ ideg, int* __restrict__ gcnt) {
    int b = blockIdx.x;
    if (b < 512) {
        int i = b * 256 + threadIdx.x, st = 512 * 256;
        for (; i < E; i += st) atomicAdd(&ideg[dst[i]], 1);
    } else {
        int i = (b - 512) * 256 + threadIdx.x, st = 128 * 256;
        for (; i < N; i += st) atomicAdd(&gcnt[batch[i]], 1);
    }
}

// single-block two-level exclusive scan; writes out[n]=total, optional 2nd copy
static __device__ void scan_block(const int* __restrict__ in, int* __restrict__ out,
                                  int* __restrict__ out2, int n, int* wsum) {
    const int tid = threadIdx.x;
    const int lane = tid & 63, wv = tid >> 6;
    const int C = (n + 1023) >> 10;
    const int base = tid * C;
    int s = 0;
    for (int k = 0; k < C; ++k) {
        int i = base + k;
        if (i < n) s += in[i];
    }
    int incl = s;
#pragma unroll
    for (int off = 1; off < 64; off <<= 1) {
        int t = __shfl_up(incl, off);
        if (lane >= off) incl += t;
    }
    if (lane == 63) wsum[wv] = incl;
    __syncthreads();
    int woff = 0;
    for (int i2 = 0; i2 < wv; ++i2) woff += wsum[i2];
    int excl = woff + incl - s;
    int run = excl;
    for (int k = 0; k < C; ++k) {
        int i = base + k;
        if (i < n) {
            out[i] = run;
            if (out2) out2[i] = run;
            run += in[i];
        }
    }
    if (tid == 1023) out[n] = run;
    __syncthreads();
}

__global__ __launch_bounds__(1024) void k_scan_all(
    const int* __restrict__ ideg, int* __restrict__ rowptr, int* __restrict__ cursor, int n1,
    const int* __restrict__ gcnt, int* __restrict__ gptr, int n2) {
    __shared__ int wsum[16];
    scan_block(ideg, rowptr, cursor, n1, wsum);
    scan_block(gcnt, gptr, nullptr, n2, wsum);
}

// bucket edges by dst + pad tail [E, Epad)
__global__ void k_scatter(const int* __restrict__ ei, int E, int Epad,
                          int* __restrict__ cursor, int* __restrict__ eid_s,
                          int* __restrict__ esrc_s, int* __restrict__ dst_s,
                          unsigned short* __restrict__ ea_s) {
    int i = blockIdx.x * blockDim.x + threadIdx.x;
    int st = gridDim.x * blockDim.x;
    for (int k = i; k < E; k += st) {
        int d = ei[E + k];
        int pos = atomicAdd(&cursor[d], 1);
        eid_s[pos] = k;
        esrc_s[pos] = ei[k];
        dst_s[pos] = d;
    }
    if (i < Epad - E) {
        esrc_s[E + i] = 0;
        dst_s[E + i] = -1;
        us4 z = {0, 0, 0, 0};
        us4* p = (us4*)(ea_s + (size_t)(E + i) * 32);
#pragma unroll
        for (int q = 0; q < 8; ++q) p[q] = z;
    }
}

// ea_s[pos] = bf16(ea[eid_s[pos]]), CSR order
__global__ void k_permute_ea(const float* __restrict__ ea, const int* __restrict__ eid_s,
                             unsigned short* __restrict__ ea_s, int E) {
    int i = blockIdx.x * blockDim.x + threadIdx.x;
    int st = gridDim.x * blockDim.x;
    const int ng = E * 4;
    for (; i < ng; i += st) {
        int pos = i >> 2, q = i & 3;
        int e = eid_s[pos];
        const float4* sp = (const float4*)(ea + (size_t)e * 32 + q * 8);
        float4 a = sp[0], b = sp[1];
        us4 o0, o1;
        o0.x = f2bf(a.x); o0.y = f2bf(a.y); o0.z = f2bf(a.z); o0.w = f2bf(a.w);
        o1.x = f2bf(b.x); o1.y = f2bf(b.y); o1.z = f2bf(b.z); o1.w = f2bf(b.w);
        us4* dp = (us4*)(ea_s + (size_t)pos * 32 + q * 8);
        dp[0] = o0; dp[1] = o1;
    }
}

// weight prep: bf16 casts of we1/2/3, wn1/2/3 + w4 transpose with permuted rows
__global__ void k_wprep(const float* __restrict__ we1, const float* __restrict__ we2,
                        const float* __restrict__ we3, const float* __restrict__ wn1,
                        const float* __restrict__ wn2, const float* __restrict__ wn3,
                        const float* __restrict__ w4,
                        unsigned short* __restrict__ webf1, unsigned short* __restrict__ webf2,
                        unsigned short* __restrict__ webf3, unsigned short* __restrict__ wnbf1,
                        unsigned short* __restrict__ wnbf2, unsigned short* __restrict__ wnbf3,
                        float* __restrict__ w4t) {
    int idx = blockIdx.x * blockDim.x + threadIdx.x;
    const float* s; unsigned short* d; int rel;
    if (idx < 512)        { s = we1; d = webf1; rel = idx; }
    else if (idx < 2560)  { s = we2; d = webf2; rel = idx - 512; }
    else if (idx < 4608)  { s = we3; d = webf3; rel = idx - 2560; }
    else if (idx < 8704)  { s = wn1; d = wnbf1; rel = idx - 4608; }
    else if (idx < 25088) { s = wn2; d = wnbf2; rel = idx - 8704; }
    else if (idx < 41472) { s = wn3; d = wnbf3; rel = idx - 25088; }
    else if (idx < 49664) {
        int rel2 = idx - 41472;
        int k = rel2 >> 5;                 // position 0..255 in permuted pooled vec
        int j0 = (rel2 & 31) * 4;
        // channel held at position k: (k&~63) + (k&3)*16 + ((k&63)>>2)
        int ck = (k & 0xC0) | (((k & 3) * 16) + ((k & 63) >> 2));
        float4 o;
        o.x = w4[(j0 + 0) * 256 + ck]; o.y = w4[(j0 + 1) * 256 + ck];
        o.z = w4[(j0 + 2) * 256 + ck]; o.w = w4[(j0 + 3) * 256 + ck];
        *(float4*)(w4t + k * 128 + j0) = o;
        return;
    } else return;
    float4 t = ((const float4*)s)[rel];
    us4 o; o.x = f2bf(t.x); o.y = f2bf(t.y); o.z = f2bf(t.z); o.w = f2bf(t.w);
    ((us4*)d)[rel] = o;
}

// x -> permuted bf16 x_bf + natural f32 self-term init
__global__ void k_xprep(const float* __restrict__ x, unsigned short* __restrict__ x_bf,
                        float* __restrict__ aggrA, int n16) {
    int i = blockIdx.x * blockDim.x + threadIdx.x;
    int st = gridDim.x * blockDim.x;
    for (; i < n16; i += st) {
        int n = i >> 4, j = i & 15;
        // natural f32 copy (positions j*4..j*4+3 == channels j*4..j*4+3)
        float4 t = *(const float4*)(x + (size_t)n * 64 + j * 4);
        ((float4*)aggrA)[i] = t;
        // permuted bf16: position j*4+t holds channel t*16+j
        us4 o;
        o.x = f2bf(x[(size_t)n * 64 + j]);
        o.y = f2bf(x[(size_t)n * 64 + 16 + j]);
        o.z = f2bf(x[(size_t)n * 64 + 32 + j]);
        o.w = f2bf(x[(size_t)n * 64 + 48 + j]);
        *(us4*)(x_bf + (size_t)n * 64 + j * 4) = o;
    }
}

// ---------------------------------------------------------------------------
// Edge kernel. Round-6 structure (1 tile/wave, contiguous-64B atomic flush,
// channel c = colbase + t*16 + l15) + permuted-h 8B gathers.
// aggr must be pre-initialized with the self term (f32, natural layout).
// ---------------------------------------------------------------------------
template<int D>
__global__ __launch_bounds__(256) void k_edge_mfma(
    const unsigned short* __restrict__ hbf,   // [N][D] bf16, PERMUTED layout
    const unsigned short* __restrict__ ea_s,  // [Epad][32] bf16, CSR order
    const int* __restrict__ esrc_s,           // [Epad]
    const int* __restrict__ dst_s,            // [Epad]
    const unsigned short* __restrict__ webf,  // [D][32] bf16, natural rows
    const float* __restrict__ be,             // [D]
    float* __restrict__ aggr,                 // [N][D] f32, natural layout
    int E)
{
    const int tid = threadIdx.x;
    const int lane = tid & 63;
    const int w = tid >> 6;
    const int l15 = lane & 15;
    const int lhi = lane >> 4;

    const int wavetile = (D == 256) ? (int)blockIdx.x : ((int)blockIdx.x * 4 + w);
    const int colbase  = (D == 256) ? (w * 64) : 0;
    const int e0 = wavetile * 64;
    if (e0 >= E) return;

    const int dstreg = dst_s[e0 + lane];

    int4 src4[4];
#pragma unroll
    for (int q = 0; q < 4; ++q)
        src4[q] = *(const int4*)(esrc_s + e0 + q * 16 + lhi * 4);

    short8v afr[4];
#pragma unroll
    for (int q = 0; q < 4; ++q)
        afr[q] = *(const short8v*)(ea_s + (size_t)(e0 + q * 16 + l15) * 32 + lhi * 8);

    short8v bfr[4]; float bias[4];
#pragma unroll
    for (int t = 0; t < 4; ++t) {
        int c = colbase + t * 16 + l15;
        bfr[t] = *(const short8v*)(webf + (size_t)c * 32 + lhi * 8);
        bias[t] = be[c];
    }

    // permuted h-gather: one us4 per fragment row -> channels {t*16+l15}
    us4 hv[4][4];
#pragma unroll
    for (int q = 0; q < 4; ++q) {
        const int sr[4] = {src4[q].x, src4[q].y, src4[q].z, src4[q].w};
#pragma unroll
        for (int i = 0; i < 4; ++i)
            hv[q][i] = *(const us4*)(hbf + (size_t)sr[i] * D + colbase + l15 * 4);
    }

    f32x4 acc[4][4];
#pragma unroll
    for (int q = 0; q < 4; ++q)
#pragma unroll
        for (int t = 0; t < 4; ++t) {
            f32x4 ci; ci[0] = bias[t]; ci[1] = bias[t]; ci[2] = bias[t]; ci[3] = bias[t];
            acc[q][t] = __builtin_amdgcn_mfma_f32_16x16x32_bf16(afr[q], bfr[t], ci, 0, 0, 0);
        }

    // m = relu(el + h_src)
#pragma unroll
    for (int q = 0; q < 4; ++q)
#pragma unroll
        for (int i = 0; i < 4; ++i) {
            us4 h4 = hv[q][i];
#pragma unroll
            for (int t = 0; t < 4; ++t)
                acc[q][t][i] = fmaxf(acc[q][t][i] + bf2f(h4[t]), 0.0f);
        }

    // segmented flush over sorted dst (contiguous 64B atomics per t)
    int dprev = __shfl_up(dstreg, 1);
    bool bflag = (lane > 0) && (dstreg != dprev);
    unsigned long long bmask = __ballot(bflag);
    const int nseg = __builtin_popcountll(bmask) + 1;
    unsigned mlo = (unsigned)bmask, mhi = (unsigned)(bmask >> 32);
    const int segid_lane =
        __builtin_amdgcn_mbcnt_hi(mhi, __builtin_amdgcn_mbcnt_lo(mlo, 0)) + (bflag ? 1 : 0);

    int segid_qi[4][4];
#pragma unroll
    for (int q = 0; q < 4; ++q)
#pragma unroll
        for (int i = 0; i < 4; ++i) {
            int row = q * 16 + lhi * 4 + i;
            unsigned long long p = 1ull << row;
            segid_qi[q][i] = __builtin_popcountll(bmask & (p | (p - 1ull)));
        }

    for (int s = 0; s < nseg; ++s) {
        float a[4] = {0.0f, 0.0f, 0.0f, 0.0f};
#pragma unroll
        for (int q = 0; q < 4; ++q)
#pragma unroll
            for (int i = 0; i < 4; ++i) {
                bool tk = (segid_qi[q][i] == s);
#pragma unroll
                for (int t = 0; t < 4; ++t) a[t] += tk ? acc[q][t][i] : 0.0f;
            }
#pragma unroll
        for (int t = 0; t < 4; ++t) {
            a[t] += __shfl_xor(a[t], 16);
            a[t] += __shfl_xor(a[t], 32);
        }
        unsigned long long ms = __ballot(segid_lane == s);
        int fl = (int)__builtin_ctzll(ms);
        int dseg = __shfl(dstreg, fl);
        if (dseg >= 0 && lhi == 0) {
#pragma unroll
            for (int t = 0; t < 4; ++t)
                atomicAdd(aggr + (size_t)dseg * D + colbase + t * 16 + l15, a[t]);
        }
    }
}

// ---------------------------------------------------------------------------
// MFMA node GEMM + BN + ReLU. Natural aggr in/out; h_bf stored PERMUTED via
// two 16B stores per row-fragment (lane's 16 channels are contiguous there).
// ---------------------------------------------------------------------------
template<int K, bool AW>
__global__ __launch_bounds__(256) void k_node_mfma(
    const float* __restrict__ A, const unsigned short* __restrict__ wnbf,
    const float* __restrict__ bnb, const float* __restrict__ g,
    const float* __restrict__ b, const float* __restrict__ rm,
    const float* __restrict__ rv, unsigned short* __restrict__ out,
    float* __restrict__ aggr_out, int N)
{
    const int tid = threadIdx.x;
    const int lane = tid & 63;
    const int w = tid >> 6;
    const int l15 = lane & 15;
    const int lhi = lane >> 4;
    const int row0 = blockIdx.x * 64;
    const int ncol0 = w * 64;

    f32x4 scale[4], shift[4];
    f32x4 acc[4][4];
#pragma unroll
    for (int q = 0; q < 4; ++q) {
        int n0 = ncol0 + q * 16 + lhi * 4;
        float4 gg = *(const float4*)(g + n0);
        float4 rvv = *(const float4*)(rv + n0);
        float4 bb = *(const float4*)(b + n0);
        float4 rmm = *(const float4*)(rm + n0);
        float4 bn = *(const float4*)(bnb + n0);
        f32x4 sc, sh, ci;
        sc[0] = gg.x * rsqrtf(rvv.x + 1e-5f);
        sc[1] = gg.y * rsqrtf(rvv.y + 1e-5f);
        sc[2] = gg.z * rsqrtf(rvv.z + 1e-5f);
        sc[3] = gg.w * rsqrtf(rvv.w + 1e-5f);
        sh[0] = bb.x - rmm.x * sc[0];
        sh[1] = bb.y - rmm.y * sc[1];
        sh[2] = bb.z - rmm.z * sc[2];
        sh[3] = bb.w - rmm.w * sc[3];
        ci[0] = bn.x; ci[1] = bn.y; ci[2] = bn.z; ci[3] = bn.w;
        scale[q] = sc; shift[q] = sh;
#pragma unroll
        for (int r = 0; r < 4; ++r) acc[q][r] = ci;
    }

    for (int k0 = 0; k0 < K; k0 += 32) {
        short8v wfr[4];
#pragma unroll
        for (int q = 0; q < 4; ++q)
            wfr[q] = *(const short8v*)(wnbf + (size_t)(ncol0 + q * 16 + l15) * K + k0 + lhi * 8);
        short8v afr[4];
#pragma unroll
        for (int r = 0; r < 4; ++r) {
            const float* ap = A + (size_t)(row0 + r * 16 + l15) * K + k0 + lhi * 8;
            float4 a0 = ((const float4*)ap)[0];
            float4 a1 = ((const float4*)ap)[1];
            short8v t;
            t[0] = (short)f2bf(a0.x); t[1] = (short)f2bf(a0.y);
            t[2] = (short)f2bf(a0.z); t[3] = (short)f2bf(a0.w);
            t[4] = (short)f2bf(a1.x); t[5] = (short)f2bf(a1.y);
            t[6] = (short)f2bf(a1.z); t[7] = (short)f2bf(a1.w);
            afr[r] = t;
        }
#pragma unroll
        for (int q = 0; q < 4; ++q)
#pragma unroll
            for (int r = 0; r < 4; ++r)
                acc[q][r] = __builtin_amdgcn_mfma_f32_16x16x32_bf16(wfr[q], afr[r], acc[q][r], 0, 0, 0);
    }

#pragma unroll
    for (int r = 0; r < 4; ++r) {
        int m = row0 + r * 16 + l15;
        if (m < N) {
            f32x4 o4[4];
#pragma unroll
            for (int q = 0; q < 4; ++q) {
                int n0 = ncol0 + q * 16 + lhi * 4;
                f32x4 v = acc[q][r];
                f32x4 o;
#pragma unroll
                for (int i = 0; i < 4; ++i)
                    o[i] = fmaxf(v[i] * scale[q][i] + shift[q][i], 0.0f);
                o4[q] = o;
                if (AW) *(f32x4*)(aggr_out + (size_t)m * 256 + n0) = o;
            }
            // permuted h store: position ncol0 + lhi*16 + (i*4+q) holds
            // channel ncol0 + q*16 + lhi*4 + i  -> lane's 16 values contiguous
            us8 lo, hi;
#pragma unroll
            for (int q = 0; q < 4; ++q)
#pragma unroll
                for (int i = 0; i < 4; ++i) {
                    int p = i * 4 + q;
                    unsigned short v = f2bf(o4[q][i]);
                    if (p < 8) lo[p] = v; else hi[p - 8] = v;
                }
            *(us8*)(out + (size_t)m * 256 + ncol0 + lhi * 16) = lo;
            *(us8*)(out + (size_t)m * 256 + ncol0 + lhi * 16 + 8) = hi;
        }
    }
}

// Fused global-mean-pool + MLP head (h in PERMUTED bf16; w4t pre-permuted).
__global__ __launch_bounds__(256) void k_pool_head(
    const unsigned short* __restrict__ h, const int* __restrict__ gptr,
    const float* __restrict__ w4t, const float* __restrict__ b4,
    const float* __restrict__ w5, const float* __restrict__ b5,
    float* __restrict__ out)
{
    __shared__ float pl[256];
    __shared__ float zs[128];
    const int g = blockIdx.x;
    const int tid = threadIdx.x;
    int beg = gptr[g], end = gptr[g + 1];
    float acc = 0.0f;
    for (int r = beg; r < end; ++r) acc += bf2f(h[(size_t)r * 256 + tid]);
    float cnt = (float)(end - beg);
    pl[tid] = acc / fmaxf(cnt, 1.0f);
    __syncthreads();
    if (tid < 128) {
        float a = b4[tid];
        for (int k = 0; k < 256; ++k) a += pl[k] * w4t[k * 128 + tid];
        zs[tid] = fmaxf(a, 0.0f);
    }
    __syncthreads();
    if (tid < 64) {
        float v = zs[tid] * w5[tid] + zs[tid + 64] * w5[tid + 64];
#pragma unroll
        for (int off = 32; off > 0; off >>= 1) v += __shfl_down(v, off);
        if (tid == 0) out[g] = 1.0f / (1.0f + expf(-(v + b5[0])));
    }
}

extern "C" void kernel_launch(void* const* d_in, const int* in_sizes, int n_in,
                              void* d_out, int out_size, void* d_ws, size_t ws_size,
                              hipStream_t stream)
{
    const float* x    = (const float*)d_in[0];
    const int*   ei   = (const int*)d_in[1];
    const float* ea   = (const float*)d_in[2];
    const int*   batch= (const int*)d_in[3];
    const float* we1  = (const float*)d_in[4];
    const float* be1  = (const float*)d_in[5];
    const float* wn1  = (const float*)d_in[6];
    const float* bnb1 = (const float*)d_in[7];
    const float* we2  = (const float*)d_in[8];
    const float* be2  = (const float*)d_in[9];
    const float* wn2  = (const float*)d_in[10];
    const float* bnb2 = (const float*)d_in[11];
    const float* we3  = (const float*)d_in[12];
    const float* be3  = (const float*)d_in[13];
    const float* wn3  = (const float*)d_in[14];
    const float* bnb3 = (const float*)d_in[15];
    const float* g1 = (const float*)d_in[16];
    const float* b1 = (const float*)d_in[17];
    const float* rm1= (const float*)d_in[18];
    const float* rv1= (const float*)d_in[19];
    const float* g2 = (const float*)d_in[20];
    const float* b2 = (const float*)d_in[21];
    const float* rm2= (const float*)d_in[22];
    const float* rv2= (const float*)d_in[23];
    const float* g3 = (const float*)d_in[24];
    const float* b3 = (const float*)d_in[25];
    const float* rm3= (const float*)d_in[26];
    const float* rv3= (const float*)d_in[27];
    const float* w4 = (const float*)d_in[28];
    const float* b4 = (const float*)d_in[29];
    const float* w5 = (const float*)d_in[30];
    const float* b5 = (const float*)d_in[31];

    const int N = in_sizes[0] / 64;
    const int E = in_sizes[1] / 2;
    const int G = out_size;
    const int Epad = (E + 63) & ~63;

    // ---- workspace layout ----
    float* ws    = (float*)d_ws;
    float* aggrA = ws;                                  // N*256 f32
    float* aggrB = aggrA + (size_t)N * 256;             // N*256 f32
    float* w4t   = aggrB + (size_t)N * 256;             // 256*128
    unsigned short* ea_s  = (unsigned short*)(w4t + 256 * 128);   // Epad*32 bf16
    unsigned short* x_bf  = ea_s + (size_t)Epad * 32;   // N*64 bf16 (permuted)
    unsigned short* h_bf  = x_bf + (size_t)N * 64;      // N*256 bf16 (permuted)
    unsigned short* webf1 = h_bf + (size_t)N * 256;     // 64*32 bf16
    unsigned short* webf2 = webf1 + 64 * 32;            // 256*32
    unsigned short* webf3 = webf2 + 256 * 32;           // 256*32
    unsigned short* wnbf1 = webf3 + 256 * 32;           // 256*64 bf16
    unsigned short* wnbf2 = wnbf1 + 256 * 64;           // 256*256
    unsigned short* wnbf3 = wnbf2 + 256 * 256;          // 256*256
    int* iws    = (int*)(wnbf3 + 256 * 256);
    int* ideg   = iws;                                  // N   (gcnt adjacent!)
    int* gcnt   = ideg + N;                             // G
    int* rowptr = gcnt + G;                             // N+1
    int* gptr   = rowptr + N + 1;                       // G+1
    int* cursor = gptr + G + 1;                         // N
    int* eid_s  = cursor + N;                           // E
    int* esrc_s = eid_s + E;                            // Epad
    int* dst_s  = esrc_s + Epad;                        // Epad

    const int nblk64  = (N + 63) / 64;
    const int eblk256 = (E + 63) / 64;
    const int eblk64  = (E + 255) / 256;

    // ---- fused preprocessing ----
    k_zero_i<<<64, 256, 0, stream>>>(ideg, N + G);
    k_hist2<<<640, 256, 0, stream>>>(ei + E, E, batch, N, ideg, gcnt);
    k_scan_all<<<1, 1024, 0, stream>>>(ideg, rowptr, cursor, N, gcnt, gptr, G);
    k_scatter<<<512, 256, 0, stream>>>(ei, E, Epad, cursor, eid_s, esrc_s, dst_s, ea_s);
    k_permute_ea<<<2048, 256, 0, stream>>>(ea, eid_s, ea_s, E);
    k_wprep<<<194, 256, 0, stream>>>(we1, we2, we3, wn1, wn2, wn3, w4,
                                     webf1, webf2, webf3, wnbf1, wnbf2, wnbf3, w4t);
    k_xprep<<<1250, 256, 0, stream>>>(x, x_bf, aggrA, N * 16);

    // ---- Layer 1 (D=64) ----
    k_edge_mfma<64><<<eblk64, 256, 0, stream>>>(
        x_bf, ea_s, esrc_s, dst_s, webf1, be1, aggrA, E);
    k_node_mfma<64, true><<<nblk64, 256, 0, stream>>>(aggrA, wnbf1, bnb1, g1, b1, rm1, rv1,
                                                      h_bf, aggrB, N);

    // ---- Layer 2 (D=256) ----
    k_edge_mfma<256><<<eblk256, 256, 0, stream>>>(
        h_bf, ea_s, esrc_s, dst_s, webf2, be2, aggrB, E);
    k_node_mfma<256, true><<<nblk64, 256, 0, stream>>>(aggrB, wnbf2, bnb2, g2, b2, rm2, rv2,
                                                       h_bf, aggrA, N);

    // ---- Layer 3 (D=256) ----
    k_edge_mfma<256><<<eblk256, 256, 0, stream>>>(
        h_bf, ea_s, esrc_s, dst_s, webf3, be3, aggrA, E);
    k_node_mfma<256, false><<<nblk64, 256, 0, stream>>>(aggrA, wnbf3, bnb3, g3, b3, rm3, rv3,
                                                        h_bf, (float*)nullptr, N);

    // ---- Fused pool + head ----
    k_pool_head<<<G, 256, 0, stream>>>(h_bf, gptr, w4t, b4, w5, b5, (float*)d_out);
}